// Round 3
// baseline (291.965 us; speedup 1.0000x reference)
//
#include <hip/hip_runtime.h>
#include <math.h>

#define FRAME_LEN 400
#define HOP 160
#define NMEL 80
#define PREEMPH 0.97f
#define MEL_FLOOR 1.192092955078125e-07f
#define WAVES 4
#define FPW 4          // frames per wave
#define FPB (WAVES*FPW)

__device__ __forceinline__ float2 cadd(float2 a, float2 b){ return make_float2(a.x+b.x, a.y+b.y); }
__device__ __forceinline__ float2 csub(float2 a, float2 b){ return make_float2(a.x-b.x, a.y-b.y); }
__device__ __forceinline__ float2 cmul(float2 a, float2 b){ return make_float2(a.x*b.x-a.y*b.y, a.x*b.y+a.y*b.x); }

// One frame per wave. 512-pt rFFT via real-packed 256-pt complex FFT:
//   256 = 4 (per-lane radix-4 in regs) x 64 (cross-lane radix-2 DIF, shfl_xor).
// Mel filterbank applied as a SCATTER: each bin k contributes to exactly 2
// channels (floor(u)-1, floor(u)) with weights (1-frac, frac) -> ds_add_f32
// into a per-wave 80-slot LDS accumulator. Per-channel sum/sumsq reduced
// in-kernel -> 160 double atomics per block (reduce_kernel deleted).
__global__ __launch_bounds__(256) void feat_kernel(
    const float* __restrict__ raw, const float* __restrict__ window,
    float* __restrict__ mel_out, double* __restrict__ accum, int F)
{
    __shared__ float wlds[FRAME_LEN];        // window * 32768 (scale folded in)
    __shared__ float xb[WAVES][FRAME_LEN];   // per-wave staged frame (unscaled)
    __shared__ float melacc[WAVES][88];      // per-wave channel accum (80 + dummies)
    __shared__ float blk_s[WAVES][NMEL];     // block-combine: sums
    __shared__ float blk_q[WAVES][NMEL];     // block-combine: sumsq

    const int t = threadIdx.x;
    const int l = t & 63;
    const int w = t >> 6;

    // ---- block init ----
    if (t < FRAME_LEN) wlds[t] = window[t] * 32768.f;
    if (t + 256 < FRAME_LEN) wlds[t + 256] = window[t + 256] * 32768.f;

    // ---- per-lane FFT constants ----
    const int p    = __brev((unsigned)l) >> 26;                    // bitrev6(l)
    const int src0 = __brev((unsigned)((64 - p) & 63)) >> 26;      // untangle src for reg 0
    const int sxor = l ^ 63;                                       // untangle src for regs 1..3

    float2 s3tw[5];                 // DIF stage twiddles, stages 0..4 (stage 5 = identity)
    float  sg[6];                   // butterfly sign: -1 on high lanes
    #pragma unroll
    for (int s = 0; s < 6; ++s) {
        int d = 32 >> s;
        sg[s] = (l & d) ? -1.f : 1.f;
        if (s < 5) {
            float2 tw = make_float2(1.f, 0.f);
            if (l & d) {
                float e = (float)((l & (d - 1)) * (32 / d));
                float ang = -6.283185307179586f * e * (1.0f / 64.0f);
                sincosf(ang, &tw.y, &tw.x);
            }
            s3tw[s] = tw;
        }
    }
    float2 w2[4];                   // four-step twiddles W_256^{l q}
    #pragma unroll
    for (int q = 1; q < 4; ++q) {
        float ang = -6.283185307179586f * (float)(l * q) * (1.0f / 256.0f);
        sincosf(ang, &w2[q].y, &w2[q].x);
    }
    float2 wk[4];                   // rFFT untangle twiddles W_512^{k}, k = q + 4p
    #pragma unroll
    for (int q = 0; q < 4; ++q) {
        int k = q + 4 * p;
        float ang = -3.1415926535897932f * (float)k * (1.0f / 256.0f);
        sincosf(ang, &wk[q].y, &wk[q].x);
    }
    // ---- per-lane mel scatter constants (bins k = q + 4p) ----
    int   cch0[4], cch1[4];
    float wt0[4], wt1[4];
    {
        const double mel_min = 1127.0 * log(1.0 + 20.0 / 700.0);
        const double mel_max = 1127.0 * log(1.0 + 8000.0 / 700.0);
        const double dstep = (mel_max - mel_min) / 81.0;
        #pragma unroll
        for (int q = 0; q < 4; ++q) {
            int k = q + 4 * p;
            double fhz = 31.25 * (double)k;
            float u = (float)((1127.0 * log(1.0 + fhz / 700.0) - mel_min) / dstep);
            float fl = floorf(u);
            float frac = u - fl;
            int c1 = (int)fl;
            int c0 = c1 - 1;
            cch0[q] = (c0 >= 0 && c0 < NMEL) ? c0 : (80 + q);  // dummy slots 80..87
            cch1[q] = (c1 >= 0 && c1 < NMEL) ? c1 : (80 + q);
            wt0[q] = 1.f - frac;
            wt1[q] = frac;
        }
    }
    __syncthreads();

    float* xw = xb[w];
    float* mw = melacc[w];
    const int base0 = blockIdx.x * FPB + w * FPW;

    float acc_s0 = 0.f, acc_q0 = 0.f;   // channel l
    float acc_s1 = 0.f, acc_q1 = 0.f;   // channel 64+l (lanes 0..15)

    for (int fi = 0; fi < FPW; ++fi) {
        int f = base0 + fi;
        if (f >= F) break;                      // wave-uniform

        // zero channel accumulators (per-wave private; same-wave LDS ordering)
        mw[l] = 0.f;
        if (l < 16) mw[64 + l] = 0.f;

        // ---- stage frame + mean via wave reduce (unscaled; x32768 folded into wlds) ----
        const float4* g4 = (const float4*)(raw + (size_t)f * HOP);
        float4 a = g4[l];
        float4 b = make_float4(0.f, 0.f, 0.f, 0.f);
        if (l < 36) b = g4[64 + l];
        float s = a.x + a.y + a.z + a.w + b.x + b.y + b.z + b.w;
        #pragma unroll
        for (int d = 32; d; d >>= 1) s += __shfl_xor(s, d, 64);
        float K = s * (1.0f / (float)FRAME_LEN) * (1.0f - PREEMPH);  // mean*(1-p)

        ((float4*)xw)[l] = a;
        if (l < 36) ((float4*)xw)[64 + l] = b;

        // ---- preemph (+DC fold) + window -> packed z[n] = y[2n] + i y[2n+1] ----
        float2 z[4];
        #pragma unroll
        for (int r = 0; r < 4; ++r) {
            int i0 = 2 * (l + 64 * r);
            if (i0 < FRAME_LEN) {
                float x0  = xw[i0];
                float x1  = xw[i0 + 1];
                float xm1 = (i0 == 0) ? x0 : xw[i0 - 1];
                float y0  = fmaf(-PREEMPH, xm1, x0) - K;
                float y1  = fmaf(-PREEMPH, x0,  x1) - K;
                z[r] = make_float2(y0 * wlds[i0], y1 * wlds[i0 + 1]);
            } else {
                z[r] = make_float2(0.f, 0.f);
            }
        }

        // ---- per-lane radix-4 DFT over regs ----
        float2 t0 = cadd(z[0], z[2]);
        float2 t1 = csub(z[0], z[2]);
        float2 t2 = cadd(z[1], z[3]);
        float2 t3 = csub(z[1], z[3]);
        float2 Z[4];
        Z[0] = cadd(t0, t2);
        Z[2] = csub(t0, t2);
        Z[1] = make_float2(t1.x + t3.y, t1.y - t3.x);
        Z[3] = make_float2(t1.x - t3.y, t1.y + t3.x);

        // ---- twiddle W_256^{l q} ----
        #pragma unroll
        for (int q = 1; q < 4; ++q) Z[q] = cmul(Z[q], w2[q]);

        // ---- 64-pt cross-lane radix-2 DIF (sign-fma butterflies) ----
        #pragma unroll
        for (int s5 = 0; s5 < 6; ++s5) {
            int d = 32 >> s5;
            float sgn = sg[s5];
            #pragma unroll
            for (int q = 0; q < 4; ++q) {
                float ox = __shfl_xor(Z[q].x, d, 64);
                float oy = __shfl_xor(Z[q].y, d, 64);
                float tr = fmaf(sgn, Z[q].x, ox);   // lo: Z+o, hi: o-Z
                float ti = fmaf(sgn, Z[q].y, oy);
                if (s5 < 5) {
                    float2 tw = s3tw[s5];
                    Z[q].x = tr * tw.x - ti * tw.y;
                    Z[q].y = tr * tw.y + ti * tw.x;
                } else {
                    Z[q].x = tr;
                    Z[q].y = ti;
                }
            }
        }
        // lane l, reg q holds Z[k], k = q + 4p (p = bitrev6(l))

        // ---- rFFT untangle + power + mel scatter ----
        float zcr[4], zci[4];
        zcr[0] = __shfl(Z[0].x, src0, 64);
        zci[0] = __shfl(Z[0].y, src0, 64);
        zcr[1] = __shfl(Z[3].x, sxor, 64);
        zci[1] = __shfl(Z[3].y, sxor, 64);
        zcr[2] = __shfl(Z[2].x, sxor, 64);
        zci[2] = __shfl(Z[2].y, sxor, 64);
        zcr[3] = __shfl(Z[1].x, sxor, 64);
        zci[3] = __shfl(Z[1].y, sxor, 64);
        #pragma unroll
        for (int q = 0; q < 4; ++q) {
            float Er = 0.5f * (Z[q].x + zcr[q]);
            float Ei = 0.5f * (Z[q].y - zci[q]);
            float Or = 0.5f * (Z[q].y + zci[q]);
            float Oi = 0.5f * (zcr[q] - Z[q].x);
            float Xr = Er + Or * wk[q].x - Oi * wk[q].y;
            float Xi = Ei + Or * wk[q].y + Oi * wk[q].x;
            float pw = Xr * Xr + Xi * Xi;
            atomicAdd(&mw[cch0[q]], pw * wt0[q]);
            atomicAdd(&mw[cch1[q]], pw * wt1[q]);
        }

        // ---- log + store + running sum/sumsq (same-wave LDS ordering) ----
        {
            float v0 = __logf(fmaxf(mw[l], MEL_FLOOR));
            mel_out[(size_t)f * NMEL + l] = v0;
            acc_s0 += v0; acc_q0 = fmaf(v0, v0, acc_q0);
            if (l < 16) {
                float v1 = __logf(fmaxf(mw[64 + l], MEL_FLOOR));
                mel_out[(size_t)f * NMEL + 64 + l] = v1;
                acc_s1 += v1; acc_q1 = fmaf(v1, v1, acc_q1);
            }
        }
    }

    // ---- block combine -> 160 double atomics ----
    blk_s[w][l] = acc_s0;
    blk_q[w][l] = acc_q0;
    if (l < 16) { blk_s[w][64 + l] = acc_s1; blk_q[w][64 + l] = acc_q1; }
    __syncthreads();
    if (t < 160) {
        int c = (t < NMEL) ? t : (t - NMEL);
        float tot;
        if (t < NMEL) tot = blk_s[0][c] + blk_s[1][c] + blk_s[2][c] + blk_s[3][c];
        else          tot = blk_q[0][c] + blk_q[1][c] + blk_q[2][c] + blk_q[3][c];
        atomicAdd(&accum[t], (double)tot);
    }
}

// Finalize mean/var (ddof=1), normalize mel in place.
// grid MUST be a multiple of 5 so stride (grid*256*4) % 80 == 0 -> channel
// index is loop-invariant (no per-iteration 64-bit modulo).
__global__ __launch_bounds__(256) void norm_kernel(
    float* __restrict__ mel, const double* __restrict__ accum, int F)
{
    __shared__ float s_mean[NMEL], s_inv[NMEL];
    int t = threadIdx.x;
    if (t < NMEL) {
        double S = accum[t], Q = accum[NMEL + t];
        double mean = S / (double)F;
        double var = (Q - S * S / (double)F) / (double)(F - 1);
        s_mean[t] = (float)mean;
        s_inv[t] = (float)(1.0 / sqrt(var + 1e-7));
    }
    __syncthreads();
    unsigned n = (unsigned)F * NMEL;
    unsigned stride = gridDim.x * 256u * 4u;
    unsigned i = (blockIdx.x * 256u + (unsigned)t) * 4u;
    int c = (int)(i % NMEL);               // invariant across iterations
    float m0 = s_mean[c],     r0 = s_inv[c];
    float m1 = s_mean[c + 1], r1 = s_inv[c + 1];
    float m2 = s_mean[c + 2], r2 = s_inv[c + 2];
    float m3 = s_mean[c + 3], r3 = s_inv[c + 3];
    for (; i < n; i += stride) {
        float4 v = *(float4*)(mel + i);
        v.x = (v.x - m0) * r0;
        v.y = (v.y - m1) * r1;
        v.z = (v.z - m2) * r2;
        v.w = (v.w - m3) * r3;
        *(float4*)(mel + i) = v;
    }
}

extern "C" void kernel_launch(void* const* d_in, const int* in_sizes, int n_in,
                              void* d_out, int out_size, void* d_ws, size_t ws_size,
                              hipStream_t stream)
{
    const float* raw = (const float*)d_in[0];
    // d_in[1] = mel_filters [257,80] — replaced by the analytic scatter form
    const float* window = (const float*)d_in[2];
    float* out = (float*)d_out;

    int N = in_sizes[0];
    int F = 1 + (N - FRAME_LEN) / HOP;   // 59998 for N=9.6e6
    double* accum = (double*)d_ws;        // 160 doubles: [sum(80) | sumsq(80)]

    hipMemsetAsync(d_ws, 0, 2 * NMEL * sizeof(double), stream);
    int gridA = (F + FPB - 1) / FPB;
    feat_kernel<<<gridA, 256, 0, stream>>>(raw, window, out, accum, F);
    norm_kernel<<<2000, 256, 0, stream>>>(out, accum, F);
}

// Round 4
// 192.188 us; speedup vs baseline: 1.5192x; 1.5192x over previous
//
#include <hip/hip_runtime.h>
#include <math.h>

#define FRAME_LEN 400
#define HOP 160
#define NMEL 80
#define PREEMPH 0.97f
#define MEL_FLOOR 1.192092955078125e-07f
#define WAVES 4
#define FPW 4          // frames per wave
#define FPB (WAVES*FPW)

__device__ __forceinline__ float2 cadd(float2 a, float2 b){ return make_float2(a.x+b.x, a.y+b.y); }
__device__ __forceinline__ float2 csub(float2 a, float2 b){ return make_float2(a.x-b.x, a.y-b.y); }
__device__ __forceinline__ float2 cmul(float2 a, float2 b){ return make_float2(a.x*b.x-a.y*b.y, a.x*b.y+a.y*b.x); }

// One frame per wave. 512-pt rFFT via real-packed 256-pt complex FFT:
//   256 = 4 (per-lane radix-4 in regs) x 64 (cross-lane radix-2 DIF, shfl_xor).
// Mel filterbank: split-product GATHER. At power-spectrum time each bin k
// stores v1[k]=pw*frac(u_k) and v0[k]=pw*(1-frac) (swizzled, conflict-free).
// Channel c = sum v1 over [ks(c),ks(c+1)) + sum v0 over [ks(c+1),ks(c+2)).
// (Round-3 LDS-atomic scatter regressed 2x: same-address ds_add_f32
//  serialization -> VALUBusy 26%. Gather is the right structure.)
__global__ __launch_bounds__(256) void feat_kernel(
    const float* __restrict__ raw, const float* __restrict__ window,
    float* __restrict__ mel_out, double* __restrict__ accum, int F)
{
    __shared__ float wlds[FRAME_LEN];        // window * 32768
    __shared__ float uu[256];                // mel-normalized bin positions
    __shared__ int   ks[82];                 // ks[c] = first k with uu[k] >= c
    __shared__ __align__(16) float xb[WAVES][FRAME_LEN];   // per-wave staged frame
    __shared__ float v1sw[WAVES][256];       // pw*frac,  swizzled [q*64+p]
    __shared__ float v0sw[WAVES][256];       // pw*(1-frac), swizzled
    __shared__ float blk_s[WAVES][NMEL];     // block-combine: sums
    __shared__ float blk_q[WAVES][NMEL];     // block-combine: sumsq

    const int t = threadIdx.x;
    const int l = t & 63;
    const int w = t >> 6;

    // ---- block init ----
    if (t < FRAME_LEN) wlds[t] = window[t] * 32768.f;
    if (t + 256 < FRAME_LEN) wlds[t + 256] = window[t + 256] * 32768.f;
    const double mel_min = 1127.0 * log(1.0 + 20.0 / 700.0);
    const double mel_max = 1127.0 * log(1.0 + 8000.0 / 700.0);
    const double dstep = (mel_max - mel_min) / 81.0;
    {
        double fhz = 31.25 * (double)t;
        double m = 1127.0 * log(1.0 + fhz / 700.0);
        uu[t] = (float)((m - mel_min) / dstep);
    }
    __syncthreads();
    if (t < 82) {
        // direct estimate of first k with uu[k] >= t, then exact fixup vs uu
        double fhz = 700.0 * (exp((mel_min + (double)t * dstep) / 1127.0) - 1.0);
        int k = (int)ceil(fhz / 31.25);
        k = max(0, min(256, k));
        while (k > 0 && uu[k - 1] >= (float)t) --k;
        while (k < 256 && uu[k] < (float)t) ++k;
        ks[t] = k;
    }

    // ---- per-lane FFT constants ----
    const int p    = __brev((unsigned)l) >> 26;                    // bitrev6(l)
    const int src0 = __brev((unsigned)((64 - p) & 63)) >> 26;      // untangle src, reg 0
    const int sxor = l ^ 63;                                       // untangle src, regs 1..3

    float2 s3tw[5];                 // DIF stage twiddles, stages 0..4 (stage 5 identity)
    float  sg[6];
    #pragma unroll
    for (int s = 0; s < 6; ++s) {
        int d = 32 >> s;
        sg[s] = (l & d) ? -1.f : 1.f;
        if (s < 5) {
            float2 tw = make_float2(1.f, 0.f);
            if (l & d) {
                float e = (float)((l & (d - 1)) * (32 / d));
                float ang = -6.283185307179586f * e * (1.0f / 64.0f);
                sincosf(ang, &tw.y, &tw.x);
            }
            s3tw[s] = tw;
        }
    }
    float2 w2[4];                   // four-step twiddles W_256^{l q}
    #pragma unroll
    for (int q = 1; q < 4; ++q) {
        float ang = -6.283185307179586f * (float)(l * q) * (1.0f / 256.0f);
        sincosf(ang, &w2[q].y, &w2[q].x);
    }
    float2 wk[4];                   // rFFT untangle twiddles W_512^{k}, k = q + 4p
    #pragma unroll
    for (int q = 0; q < 4; ++q) {
        int k = q + 4 * p;
        float ang = -3.1415926535897932f * (float)k * (1.0f / 256.0f);
        sincosf(ang, &wk[q].y, &wk[q].x);
    }
    __syncthreads();   // uu/ks ready

    // per-lane split-weight fractions for bins k = q + 4p
    float fr1[4], fr0[4];
    #pragma unroll
    for (int q = 0; q < 4; ++q) {
        float u = uu[4 * p + q];
        float fl = floorf(u);
        fr1[q] = u - fl;
        fr0[q] = 1.f - fr1[q];
    }
    // gather bounds (registers): strip1 = ch 16+l (all lanes), strip2 = ch l (lanes<16)
    const int c1ch = 16 + l;
    int a0 = ks[c1ch], b0 = ks[c1ch + 1], e0 = ks[c1ch + 2];
    int a1 = 0, b1 = 0, e1 = 0;
    if (l < 16) { a1 = ks[l]; b1 = ks[l + 1]; e1 = ks[l + 2]; }

    float* xw  = xb[w];
    float* v1w = v1sw[w];
    float* v0w = v0sw[w];
    const int base0 = blockIdx.x * FPB + w * FPW;

    float acc_s0 = 0.f, acc_q0 = 0.f;   // channel 16+l
    float acc_s1 = 0.f, acc_q1 = 0.f;   // channel l (lanes 0..15)

    for (int fi = 0; fi < FPW; ++fi) {
        int f = base0 + fi;
        if (f >= F) break;                      // wave-uniform

        // ---- stage frame + mean via wave reduce ----
        const float4* g4 = (const float4*)(raw + (size_t)f * HOP);
        float4 a = g4[l];
        float4 b = make_float4(0.f, 0.f, 0.f, 0.f);
        if (l < 36) b = g4[64 + l];
        float s = a.x + a.y + a.z + a.w + b.x + b.y + b.z + b.w;
        #pragma unroll
        for (int d = 32; d; d >>= 1) s += __shfl_xor(s, d, 64);
        float K = s * (1.0f / (float)FRAME_LEN) * (1.0f - PREEMPH);  // mean*(1-p)

        ((float4*)xw)[l] = a;
        if (l < 36) ((float4*)xw)[64 + l] = b;

        // ---- preemph (+DC fold) + window -> packed z[n] = y[2n] + i y[2n+1] ----
        float2 z[4];
        #pragma unroll
        for (int r = 0; r < 4; ++r) {
            int i0 = 2 * (l + 64 * r);
            if (i0 < FRAME_LEN) {
                float x0  = xw[i0];
                float x1  = xw[i0 + 1];
                float xm1 = (i0 == 0) ? x0 : xw[i0 - 1];
                float y0  = fmaf(-PREEMPH, xm1, x0) - K;
                float y1  = fmaf(-PREEMPH, x0,  x1) - K;
                z[r] = make_float2(y0 * wlds[i0], y1 * wlds[i0 + 1]);
            } else {
                z[r] = make_float2(0.f, 0.f);
            }
        }

        // ---- per-lane radix-4 DFT over regs ----
        float2 t0 = cadd(z[0], z[2]);
        float2 t1 = csub(z[0], z[2]);
        float2 t2 = cadd(z[1], z[3]);
        float2 t3 = csub(z[1], z[3]);
        float2 Z[4];
        Z[0] = cadd(t0, t2);
        Z[2] = csub(t0, t2);
        Z[1] = make_float2(t1.x + t3.y, t1.y - t3.x);
        Z[3] = make_float2(t1.x - t3.y, t1.y + t3.x);

        // ---- twiddle W_256^{l q} ----
        #pragma unroll
        for (int q = 1; q < 4; ++q) Z[q] = cmul(Z[q], w2[q]);

        // ---- 64-pt cross-lane radix-2 DIF (sign-fma butterflies) ----
        #pragma unroll
        for (int s5 = 0; s5 < 6; ++s5) {
            int d = 32 >> s5;
            float sgn = sg[s5];
            #pragma unroll
            for (int q = 0; q < 4; ++q) {
                float ox = __shfl_xor(Z[q].x, d, 64);
                float oy = __shfl_xor(Z[q].y, d, 64);
                float tr = fmaf(sgn, Z[q].x, ox);   // lo: Z+o, hi: o-Z
                float ti = fmaf(sgn, Z[q].y, oy);
                if (s5 < 5) {
                    float2 tw = s3tw[s5];
                    Z[q].x = tr * tw.x - ti * tw.y;
                    Z[q].y = tr * tw.y + ti * tw.x;
                } else {
                    Z[q].x = tr;
                    Z[q].y = ti;
                }
            }
        }
        // lane l, reg q holds Z[k], k = q + 4p (p = bitrev6(l))

        // ---- rFFT untangle + power + split-product store ----
        float zcr[4], zci[4];
        zcr[0] = __shfl(Z[0].x, src0, 64);
        zci[0] = __shfl(Z[0].y, src0, 64);
        zcr[1] = __shfl(Z[3].x, sxor, 64);
        zci[1] = __shfl(Z[3].y, sxor, 64);
        zcr[2] = __shfl(Z[2].x, sxor, 64);
        zci[2] = __shfl(Z[2].y, sxor, 64);
        zcr[3] = __shfl(Z[1].x, sxor, 64);
        zci[3] = __shfl(Z[1].y, sxor, 64);
        #pragma unroll
        for (int q = 0; q < 4; ++q) {
            float Er = 0.5f * (Z[q].x + zcr[q]);
            float Ei = 0.5f * (Z[q].y - zci[q]);
            float Or = 0.5f * (Z[q].y + zci[q]);
            float Oi = 0.5f * (zcr[q] - Z[q].x);
            float Xr = Er + Or * wk[q].x - Oi * wk[q].y;
            float Xi = Ei + Or * wk[q].y + Oi * wk[q].x;
            float pw = Xr * Xr + Xi * Xi;
            v1w[(q << 6) + p] = pw * fr1[q];
            v0w[(q << 6) + p] = pw * fr0[q];
        }
        // same-wave LDS ordering: ds ops from one wave complete in order

        // ---- range-sum gather + log + store + running stats ----
        {
            float acc = 0.f;
            for (int k = a0; k < b0; ++k) acc += v1w[((k & 3) << 6) + (k >> 2)];
            for (int k = b0; k < e0; ++k) acc += v0w[((k & 3) << 6) + (k >> 2)];
            float v = __logf(fmaxf(acc, MEL_FLOOR));
            mel_out[(size_t)f * NMEL + c1ch] = v;
            acc_s0 += v; acc_q0 = fmaf(v, v, acc_q0);
        }
        if (l < 16) {
            float acc = 0.f;
            for (int k = a1; k < b1; ++k) acc += v1w[((k & 3) << 6) + (k >> 2)];
            for (int k = b1; k < e1; ++k) acc += v0w[((k & 3) << 6) + (k >> 2)];
            float v = __logf(fmaxf(acc, MEL_FLOOR));
            mel_out[(size_t)f * NMEL + l] = v;
            acc_s1 += v; acc_q1 = fmaf(v, v, acc_q1);
        }
    }

    // ---- block combine -> 160 double atomics ----
    blk_s[w][c1ch] = acc_s0;
    blk_q[w][c1ch] = acc_q0;
    if (l < 16) { blk_s[w][l] = acc_s1; blk_q[w][l] = acc_q1; }
    __syncthreads();
    if (t < 160) {
        int c = (t < NMEL) ? t : (t - NMEL);
        float tot;
        if (t < NMEL) tot = blk_s[0][c] + blk_s[1][c] + blk_s[2][c] + blk_s[3][c];
        else          tot = blk_q[0][c] + blk_q[1][c] + blk_q[2][c] + blk_q[3][c];
        atomicAdd(&accum[t], (double)tot);
    }
}

// Finalize mean/var (ddof=1), normalize mel in place.
// grid multiple of 5 -> stride % 80 == 0 -> channel index loop-invariant.
__global__ __launch_bounds__(256) void norm_kernel(
    float* __restrict__ mel, const double* __restrict__ accum, int F)
{
    __shared__ float s_mean[NMEL], s_inv[NMEL];
    int t = threadIdx.x;
    if (t < NMEL) {
        double S = accum[t], Q = accum[NMEL + t];
        double mean = S / (double)F;
        double var = (Q - S * S / (double)F) / (double)(F - 1);
        s_mean[t] = (float)mean;
        s_inv[t] = (float)(1.0 / sqrt(var + 1e-7));
    }
    __syncthreads();
    unsigned n = (unsigned)F * NMEL;
    unsigned stride = gridDim.x * 256u * 4u;
    unsigned i = (blockIdx.x * 256u + (unsigned)t) * 4u;
    int c = (int)(i % NMEL);               // invariant across iterations
    float m0 = s_mean[c],     r0 = s_inv[c];
    float m1 = s_mean[c + 1], r1 = s_inv[c + 1];
    float m2 = s_mean[c + 2], r2 = s_inv[c + 2];
    float m3 = s_mean[c + 3], r3 = s_inv[c + 3];
    for (; i < n; i += stride) {
        float4 v = *(float4*)(mel + i);
        v.x = (v.x - m0) * r0;
        v.y = (v.y - m1) * r1;
        v.z = (v.z - m2) * r2;
        v.w = (v.w - m3) * r3;
        *(float4*)(mel + i) = v;
    }
}

extern "C" void kernel_launch(void* const* d_in, const int* in_sizes, int n_in,
                              void* d_out, int out_size, void* d_ws, size_t ws_size,
                              hipStream_t stream)
{
    const float* raw = (const float*)d_in[0];
    // d_in[1] = mel_filters [257,80] — replaced by the analytic split-product form
    const float* window = (const float*)d_in[2];
    float* out = (float*)d_out;

    int N = in_sizes[0];
    int F = 1 + (N - FRAME_LEN) / HOP;   // 59998 for N=9.6e6
    double* accum = (double*)d_ws;        // 160 doubles: [sum(80) | sumsq(80)]

    hipMemsetAsync(d_ws, 0, 2 * NMEL * sizeof(double), stream);
    int gridA = (F + FPB - 1) / FPB;
    feat_kernel<<<gridA, 256, 0, stream>>>(raw, window, out, accum, F);
    norm_kernel<<<2000, 256, 0, stream>>>(out, accum, F);
}

// Round 5
// 178.277 us; speedup vs baseline: 1.6377x; 1.0780x over previous
//
#include <hip/hip_runtime.h>
#include <math.h>

#define FRAME_LEN 400
#define HOP 160
#define NMEL 80
#define PREEMPH 0.97f
#define MEL_FLOOR 1.192092955078125e-07f
#define WAVES 4
#define FPW 8          // frames per wave
#define FPB (WAVES*FPW)

__device__ __forceinline__ float2 cadd(float2 a, float2 b){ return make_float2(a.x+b.x, a.y+b.y); }
__device__ __forceinline__ float2 csub(float2 a, float2 b){ return make_float2(a.x-b.x, a.y-b.y); }
__device__ __forceinline__ float2 cmul(float2 a, float2 b){ return make_float2(a.x*b.x-a.y*b.y, a.x*b.y+a.y*b.x); }

__device__ __forceinline__ float bperm(int addr, float v) {
    return __int_as_float(__builtin_amdgcn_ds_bpermute(addr, __float_as_int(v)));
}

// One frame per wave. 512-pt rFFT via real-packed 256-pt complex FFT:
//   256 = 4 (per-lane radix-4 in regs) x 64 (cross-lane radix-2 DIF, shfl_xor).
// Mel filterbank via PREFIX SUMS: logical lane p holds 4 consecutive bins
// (k=4p+q). Build inclusive prefixes of pw and pw*frac (3 local adds +
// 6-step bpermute wave scan), store b128 to LDS; each channel is then a
// closed-form combination of 5 prefix reads — no divergent gather loop.
// (R3 LDS-atomic scatter: 2x regression. R4 divergent gather: latency-bound
//  at 120us with VALUBusy only 55%.)
__global__ __launch_bounds__(256) void feat_kernel(
    const float* __restrict__ raw, const float* __restrict__ window,
    float* __restrict__ mel_out, double* __restrict__ accum, int F)
{
    __shared__ float wlds[FRAME_LEN];        // window * 32768
    __shared__ float uu[256];                // mel-normalized bin positions
    __shared__ int   ks[82];                 // ks[c] = first k with uu[k] >= c
    __shared__ __align__(16) float xb[WAVES][FRAME_LEN];   // per-wave staged frame
    __shared__ __align__(16) float pfxA[WAVES][256];  // inclusive prefix of pw
    __shared__ __align__(16) float pfxB[WAVES][256];  // inclusive prefix of pw*frac
    __shared__ float blk_s[WAVES][NMEL];     // block-combine: sums
    __shared__ float blk_q[WAVES][NMEL];     // block-combine: sumsq

    const int t = threadIdx.x;
    const int l = t & 63;
    const int w = t >> 6;

    // ---- block init ----
    if (t < FRAME_LEN) wlds[t] = window[t] * 32768.f;
    if (t + 256 < FRAME_LEN) wlds[t + 256] = window[t + 256] * 32768.f;
    const double mel_min = 1127.0 * log(1.0 + 20.0 / 700.0);
    const double mel_max = 1127.0 * log(1.0 + 8000.0 / 700.0);
    const double dstep = (mel_max - mel_min) / 81.0;
    {
        double fhz = 31.25 * (double)t;
        double m = 1127.0 * log(1.0 + fhz / 700.0);
        uu[t] = (float)((m - mel_min) / dstep);
    }
    __syncthreads();
    if (t < 82) {
        double fhz = 700.0 * (exp((mel_min + (double)t * dstep) / 1127.0) - 1.0);
        int k = (int)ceil(fhz / 31.25);
        k = max(0, min(256, k));
        while (k > 0 && uu[k - 1] >= (float)t) --k;
        while (k < 256 && uu[k] < (float)t) ++k;
        ks[t] = k;
    }

    // ---- per-lane FFT constants ----
    const int p     = __brev((unsigned)l) >> 26;                   // bitrev6(l)
    const int adr0  = (__brev((unsigned)((64 - p) & 63)) >> 26) << 2; // untangle reg0 src addr
    const int adrx  = (l ^ 63) << 2;                               // untangle regs1..3 src addr

    float2 s3tw[5];                 // DIF stage twiddles, stages 0..4 (stage 5 identity)
    float  sg[6];
    #pragma unroll
    for (int s = 0; s < 6; ++s) {
        int d = 32 >> s;
        sg[s] = (l & d) ? -1.f : 1.f;
        if (s < 5) {
            float2 tw = make_float2(1.f, 0.f);
            if (l & d) {
                float e = (float)((l & (d - 1)) * (32 / d));
                float ang = -6.283185307179586f * e * (1.0f / 64.0f);
                sincosf(ang, &tw.y, &tw.x);
            }
            s3tw[s] = tw;
        }
    }
    float2 w2[4];                   // four-step twiddles W_256^{l q}
    #pragma unroll
    for (int q = 1; q < 4; ++q) {
        float ang = -6.283185307179586f * (float)(l * q) * (1.0f / 256.0f);
        sincosf(ang, &w2[q].y, &w2[q].x);
    }
    float2 wk[4];                   // rFFT untangle twiddles W_512^{k}, k = 4p + q
    #pragma unroll
    for (int q = 0; q < 4; ++q) {
        int k = 4 * p + q;
        float ang = -3.1415926535897932f * (float)k * (1.0f / 256.0f);
        sincosf(ang, &wk[q].y, &wk[q].x);
    }
    // scan constants: step j fetches logical lane p - 2^j
    int   scadr[6];
    float scmk[6];
    #pragma unroll
    for (int j = 0; j < 6; ++j) {
        int s = 1 << j;
        scadr[j] = (int)((__brev((unsigned)((p - s) & 63)) >> 26) << 2);
        scmk[j]  = (p >= s) ? 1.f : 0.f;
    }
    __syncthreads();   // uu/ks ready

    // per-lane fractions for bins k = 4p + q
    float fr1[4];
    #pragma unroll
    for (int q = 0; q < 4; ++q) {
        float u = uu[4 * p + q];
        fr1[q] = u - floorf(u);
    }
    // channel bounds: ch0 = l (all lanes), ch1 = 64+l (lanes < 16)
    int a0 = ks[l], b0 = ks[l + 1], e0 = ks[l + 2];
    int a1 = 1, b1 = 1, e1 = 1;
    if (l < 16) { a1 = ks[64 + l]; b1 = ks[65 + l]; e1 = ks[66 + l]; }

    float* xw = xb[w];
    float* pA = pfxA[w];
    float* pB = pfxB[w];
    const int base0 = blockIdx.x * FPB + w * FPW;

    float acc_s0 = 0.f, acc_q0 = 0.f;   // channel l
    float acc_s1 = 0.f, acc_q1 = 0.f;   // channel 64+l (lanes 0..15)

    for (int fi = 0; fi < FPW; ++fi) {
        int f = base0 + fi;
        if (f >= F) break;                      // wave-uniform

        // ---- stage frame + mean via wave reduce ----
        const float4* g4 = (const float4*)(raw + (size_t)f * HOP);
        float4 a = g4[l];
        float4 b = make_float4(0.f, 0.f, 0.f, 0.f);
        if (l < 36) b = g4[64 + l];
        float s = a.x + a.y + a.z + a.w + b.x + b.y + b.z + b.w;
        #pragma unroll
        for (int d = 32; d; d >>= 1) s += __shfl_xor(s, d, 64);
        float K = s * (1.0f / (float)FRAME_LEN) * (1.0f - PREEMPH);  // mean*(1-p)

        ((float4*)xw)[l] = a;
        if (l < 36) ((float4*)xw)[64 + l] = b;

        // ---- preemph (+DC fold) + window -> packed z[n] = y[2n] + i y[2n+1] ----
        float2 z[4];
        #pragma unroll
        for (int r = 0; r < 4; ++r) {
            int i0 = 2 * (l + 64 * r);
            if (i0 < FRAME_LEN) {
                float x0  = xw[i0];
                float x1  = xw[i0 + 1];
                float xm1 = (i0 == 0) ? x0 : xw[i0 - 1];
                float y0  = fmaf(-PREEMPH, xm1, x0) - K;
                float y1  = fmaf(-PREEMPH, x0,  x1) - K;
                z[r] = make_float2(y0 * wlds[i0], y1 * wlds[i0 + 1]);
            } else {
                z[r] = make_float2(0.f, 0.f);
            }
        }

        // ---- per-lane radix-4 DFT over regs ----
        float2 t0 = cadd(z[0], z[2]);
        float2 t1 = csub(z[0], z[2]);
        float2 t2 = cadd(z[1], z[3]);
        float2 t3 = csub(z[1], z[3]);
        float2 Z[4];
        Z[0] = cadd(t0, t2);
        Z[2] = csub(t0, t2);
        Z[1] = make_float2(t1.x + t3.y, t1.y - t3.x);
        Z[3] = make_float2(t1.x - t3.y, t1.y + t3.x);

        // ---- twiddle W_256^{l q} ----
        #pragma unroll
        for (int q = 1; q < 4; ++q) Z[q] = cmul(Z[q], w2[q]);

        // ---- 64-pt cross-lane radix-2 DIF (sign-fma butterflies) ----
        #pragma unroll
        for (int s5 = 0; s5 < 6; ++s5) {
            int d = 32 >> s5;
            float sgn = sg[s5];
            #pragma unroll
            for (int q = 0; q < 4; ++q) {
                float ox = __shfl_xor(Z[q].x, d, 64);
                float oy = __shfl_xor(Z[q].y, d, 64);
                float tr = fmaf(sgn, Z[q].x, ox);   // lo: Z+o, hi: o-Z
                float ti = fmaf(sgn, Z[q].y, oy);
                if (s5 < 5) {
                    float2 tw = s3tw[s5];
                    Z[q].x = tr * tw.x - ti * tw.y;
                    Z[q].y = tr * tw.y + ti * tw.x;
                } else {
                    Z[q].x = tr;
                    Z[q].y = ti;
                }
            }
        }
        // lane l, reg q holds Z[k], k = 4p + q (p = bitrev6(l))

        // ---- rFFT untangle + power ----
        float zcr[4], zci[4];
        zcr[0] = bperm(adr0, Z[0].x);
        zci[0] = bperm(adr0, Z[0].y);
        zcr[1] = bperm(adrx, Z[3].x);
        zci[1] = bperm(adrx, Z[3].y);
        zcr[2] = bperm(adrx, Z[2].x);
        zci[2] = bperm(adrx, Z[2].y);
        zcr[3] = bperm(adrx, Z[1].x);
        zci[3] = bperm(adrx, Z[1].y);
        float pw[4], pv[4];
        #pragma unroll
        for (int q = 0; q < 4; ++q) {
            float Er = 0.5f * (Z[q].x + zcr[q]);
            float Ei = 0.5f * (Z[q].y - zci[q]);
            float Or = 0.5f * (Z[q].y + zci[q]);
            float Oi = 0.5f * (zcr[q] - Z[q].x);
            float Xr = Er + Or * wk[q].x - Oi * wk[q].y;
            float Xi = Ei + Or * wk[q].y + Oi * wk[q].x;
            pw[q] = Xr * Xr + Xi * Xi;
            pv[q] = pw[q] * fr1[q];
        }

        // ---- local inclusive prefixes over 4 consecutive bins ----
        float A0 = pw[0], A1 = A0 + pw[1], A2 = A1 + pw[2], A3 = A2 + pw[3];
        float B0 = pv[0], B1 = B0 + pv[1], B2 = B1 + pv[2], B3 = B2 + pv[3];

        // ---- wave scan over logical lane totals (Hillis-Steele, 6 steps) ----
        float xa = A3, xbv = B3;
        #pragma unroll
        for (int j = 0; j < 6; ++j) {
            float fa = bperm(scadr[j], xa);
            float fb = bperm(scadr[j], xbv);
            xa  = fmaf(scmk[j], fa, xa);
            xbv = fmaf(scmk[j], fb, xbv);
        }
        float exA = xa - A3;      // exclusive wave prefix
        float exB = xbv - B3;

        // ---- write inclusive prefixes (natural bin order, b128) ----
        ((float4*)pA)[p] = make_float4(exA + A0, exA + A1, exA + A2, exA + A3);
        ((float4*)pB)[p] = make_float4(exB + B0, exB + B1, exB + B2, exB + B3);
        // same-wave LDS ordering: subsequent reads see these writes

        // ---- closed-form channel values: 2*E1(b) - E1(a) - E1(e) + EA(e) - EA(b)
        //      where E(x) = inclusive[x-1]  (all bounds >= 1) ----
        {
            float E1a = pB[a0 - 1], E1b = pB[b0 - 1], E1e = pB[e0 - 1];
            float EAb = pA[b0 - 1], EAe = pA[e0 - 1];
            float acc = fmaf(2.f, E1b, -E1a) - E1e + (EAe - EAb);
            float v = __logf(fmaxf(acc, MEL_FLOOR));
            mel_out[(size_t)f * NMEL + l] = v;
            acc_s0 += v; acc_q0 = fmaf(v, v, acc_q0);
        }
        if (l < 16) {
            float E1a = pB[a1 - 1], E1b = pB[b1 - 1], E1e = pB[e1 - 1];
            float EAb = pA[b1 - 1], EAe = pA[e1 - 1];
            float acc = fmaf(2.f, E1b, -E1a) - E1e + (EAe - EAb);
            float v = __logf(fmaxf(acc, MEL_FLOOR));
            mel_out[(size_t)f * NMEL + 64 + l] = v;
            acc_s1 += v; acc_q1 = fmaf(v, v, acc_q1);
        }
    }

    // ---- block combine -> 160 double atomics ----
    blk_s[w][l] = acc_s0;
    blk_q[w][l] = acc_q0;
    if (l < 16) { blk_s[w][64 + l] = acc_s1; blk_q[w][64 + l] = acc_q1; }
    __syncthreads();
    if (t < 160) {
        int c = (t < NMEL) ? t : (t - NMEL);
        float tot;
        if (t < NMEL) tot = blk_s[0][c] + blk_s[1][c] + blk_s[2][c] + blk_s[3][c];
        else          tot = blk_q[0][c] + blk_q[1][c] + blk_q[2][c] + blk_q[3][c];
        atomicAdd(&accum[t], (double)tot);
    }
}

// Finalize mean/var (ddof=1), normalize mel in place.
// grid multiple of 5 -> stride % 80 == 0 -> channel index loop-invariant.
__global__ __launch_bounds__(256) void norm_kernel(
    float* __restrict__ mel, const double* __restrict__ accum, int F)
{
    __shared__ float s_mean[NMEL], s_inv[NMEL];
    int t = threadIdx.x;
    if (t < NMEL) {
        double S = accum[t], Q = accum[NMEL + t];
        double mean = S / (double)F;
        double var = (Q - S * S / (double)F) / (double)(F - 1);
        s_mean[t] = (float)mean;
        s_inv[t] = (float)(1.0 / sqrt(var + 1e-7));
    }
    __syncthreads();
    unsigned n = (unsigned)F * NMEL;
    unsigned stride = gridDim.x * 256u * 4u;
    unsigned i = (blockIdx.x * 256u + (unsigned)t) * 4u;
    int c = (int)(i % NMEL);               // invariant across iterations
    float m0 = s_mean[c],     r0 = s_inv[c];
    float m1 = s_mean[c + 1], r1 = s_inv[c + 1];
    float m2 = s_mean[c + 2], r2 = s_inv[c + 2];
    float m3 = s_mean[c + 3], r3 = s_inv[c + 3];
    for (; i < n; i += stride) {
        float4 v = *(float4*)(mel + i);
        v.x = (v.x - m0) * r0;
        v.y = (v.y - m1) * r1;
        v.z = (v.z - m2) * r2;
        v.w = (v.w - m3) * r3;
        *(float4*)(mel + i) = v;
    }
}

extern "C" void kernel_launch(void* const* d_in, const int* in_sizes, int n_in,
                              void* d_out, int out_size, void* d_ws, size_t ws_size,
                              hipStream_t stream)
{
    const float* raw = (const float*)d_in[0];
    // d_in[1] = mel_filters [257,80] — replaced by the analytic prefix form
    const float* window = (const float*)d_in[2];
    float* out = (float*)d_out;

    int N = in_sizes[0];
    int F = 1 + (N - FRAME_LEN) / HOP;   // 59998 for N=9.6e6
    double* accum = (double*)d_ws;        // 160 doubles: [sum(80) | sumsq(80)]

    hipMemsetAsync(d_ws, 0, 2 * NMEL * sizeof(double), stream);
    int gridA = (F + FPB - 1) / FPB;
    feat_kernel<<<gridA, 256, 0, stream>>>(raw, window, out, accum, F);
    norm_kernel<<<2560, 256, 0, stream>>>(out, accum, F);
}